// Round 6
// baseline (1175.339 us; speedup 1.0000x reference)
//
#include <hip/hip_runtime.h>

typedef float v2f __attribute__((ext_vector_type(2)));
typedef float v4f __attribute__((ext_vector_type(4)));

#define HH 30
#define DIN 4

#if __has_builtin(__builtin_amdgcn_exp2f)
#define EXP2F(v) __builtin_amdgcn_exp2f(v)
#else
#define EXP2F(v) exp2f(v)
#endif

// Pre-scaled sigmoid: -log2e (or -2*log2e for tanh-as-sig) folded into the
// weights/bias, so sigmoid(raw) == rcp(1 + exp2(v)) directly.
__device__ __forceinline__ float sig2f(float v) {
    return __builtin_amdgcn_rcpf(1.0f + EXP2F(v));
}

// DPP reduce step: x += dpp_shifted(x), OOB/masked lanes contribute 0
template <int Ctrl, int RowMask>
__device__ __forceinline__ float dpp_step(float x) {
    union { float f; int i; } in, out;
    in.f = x;
    out.i = __builtin_amdgcn_update_dpp(0, in.i, Ctrl, RowMask, 0xf, false);
    return x + out.f;
}
// Sum across each 32-lane half; lane31 = sum(lanes 0..31), lane63 = sum(32..63).
__device__ __forceinline__ float half_reduce(float x) {
    x = dpp_step<0x111, 0xf>(x);   // row_shr:1
    x = dpp_step<0x112, 0xf>(x);   // row_shr:2
    x = dpp_step<0x114, 0xf>(x);   // row_shr:4
    x = dpp_step<0x118, 0xf>(x);   // row_shr:8
    x = dpp_step<0x142, 0xa>(x);   // row_bcast:15 into rows 1,3
    return x;
}

// Broadcast each 32-lane half's value to all 64 lanes via permlane32_swap
// (single VALU instr, both outputs; no DS pipe). Verified R2-R5.
__device__ __forceinline__ void bcast_halves(int ahalf, float x, float& lo, float& hi) {
#if __has_builtin(__builtin_amdgcn_permlane32_swap)
    union { float f; unsigned u; } c; c.f = x;
    auto r = __builtin_amdgcn_permlane32_swap(c.u, c.u, false, false);
    union { unsigned u; float f; } o0, o1;
    o0.u = r[0];   // {x_lo, x_lo}
    o1.u = r[1];   // {x_hi, x_hi}
    lo = o0.f;
    hi = o1.f;
#else
    const float p = __shfl_xor(x, 32, 64);
    lo = ahalf ? p : x;
    hi = ahalf ? x : p;
#endif
}

// Wave-uniform broadcast of lane `l`'s value (l compile-time) -> SGPR.
__device__ __forceinline__ float lanebc(float v, int l) {
    union { float f; int i; } c; c.f = v;
    union { int i; float f; } o;
    o.i = __builtin_amdgcn_readlane(c.i, l);
    return o.f;
}

// One wave per block, one batch element per wave.
// a = lane>>5: a=0 owns (i,f) gate rows, a=1 owns (g,o) rows; h = lane&31.
//
// THIS ROUND: NO LDS. The h-vector broadcast goes through v_readlane ->
// SGPRs: after the tail, lane k holds h1n/h2n for index k; 30 readlanes
// per vector produce wave-uniform values the compiler keeps in SGPRs.
// Each matvec FMA is then v_fma_f32 vdst, v_weight, s_h, v_acc — the SGPR
// is a free operand (no splat movs, no ds_read, no lgkmcnt turnaround).
// The only memory ops left in the loop are the x prefetch and the store.
__global__ __attribute__((amdgpu_flat_work_group_size(64, 64),
                          amdgpu_waves_per_eu(2, 2)))
void lstm2_kernel(const float* __restrict__ x,
                  const float* __restrict__ Wih1, const float* __restrict__ bih1,
                  const float* __restrict__ Whh1, const float* __restrict__ bhh1,
                  const float* __restrict__ Wih2, const float* __restrict__ bih2,
                  const float* __restrict__ Whh2, const float* __restrict__ bhh2,
                  const float* __restrict__ Wlin, const float* __restrict__ blin,
                  float* __restrict__ out, int T)
{
    const int tid = threadIdx.x;
    const int a = tid >> 5;
    const int h = tid & 31;
    const bool act = (h < HH);
    const int hc = act ? h : (HH - 1);
    const int r0 = (2 * a) * HH + hc;        // i (a=0) / g (a=1) row
    const int r1 = (2 * a + 1) * HH + hc;    // f (a=0) / o (a=1) row
    const int b = blockIdx.x;

    // Row scale: i/f/o rows -log2e; g rows (r0 of half a=1) -2*log2e.
    const float L2E = 1.44269504088896340736f;
    const float sc0 = a ? -2.0f * L2E : -L2E;
    const float sc1 = -L2E;
    const float M2 = -2.0f * L2E;            // tanh(c) = 2*rcp(1+exp2(M2*c))-1

    // ---- per-lane scalar weights (pre-scaled) ----
    float wx0[DIN], wx1[DIN];
    float wh1a[HH], wh1b[HH], wi2a[HH], wi2b[HH], wh2a[HH], wh2b[HH];
#pragma unroll
    for (int c = 0; c < DIN; ++c) {
        wx0[c] = Wih1[r0 * DIN + c] * sc0;
        wx1[c] = Wih1[r1 * DIN + c] * sc1;
    }
#pragma unroll
    for (int k = 0; k < HH; ++k) {
        wh1a[k] = Whh1[r0 * HH + k] * sc0;
        wh1b[k] = Whh1[r1 * HH + k] * sc1;
        wi2a[k] = Wih2[r0 * HH + k] * sc0;
        wi2b[k] = Wih2[r1 * HH + k] * sc1;
        wh2a[k] = Whh2[r0 * HH + k] * sc0;
        wh2b[k] = Whh2[r1 * HH + k] * sc1;
    }
    const float bias1_0 = (bih1[r0] + bhh1[r0]) * sc0;
    const float bias1_1 = (bih1[r1] + bhh1[r1]) * sc1;
    const float bias2_0 = (bih2[r0] + bhh2[r0]) * sc0;
    const float bias2_1 = (bih2[r1] + bhh2[r1]) * sc1;
    const float wl0 = act ? Wlin[(2 * a) * HH + hc] : 0.0f;     // 0 on pad lanes
    const float wl1 = act ? Wlin[(2 * a + 1) * HH + hc] : 0.0f;
    const float bl0 = blin[2 * a];
    const float bl1 = blin[2 * a + 1];

    const float outS = a ? 2.0f : 1.0f;
    const float outB = a ? -1.0f : 0.0f;

    float c1 = 0.0f, c2 = 0.0f;

    // Wave-uniform h-state broadcast registers (SGPR-resident).
    float hs1[HH], hs2[HH];
#pragma unroll
    for (int k = 0; k < HH; ++k) { hs1[k] = 0.0f; hs2[k] = 0.0f; }

    const v4f* xp = reinterpret_cast<const v4f*>(x) + (size_t)b * T;
    v2f* op = reinterpret_cast<v2f*>(out) + (size_t)b * T * 2 + a;

    // ---- phase stagger: de-phase co-resident waves (numeric no-op) ----
    {
        const int phase = b & 3;
#pragma unroll 1
        for (int i = 0; i < phase; ++i)
            __builtin_amdgcn_s_sleep(7);   // ~448 cyc each
    }

    // ---- prologue: L1(0) with h1_{-1} = 0 (no Whh1 terms) ----
    {
        const v4f x0 = xp[0];
        float P0 = bias1_0, P1 = bias1_1;
        P0 = fmaf(wx0[0], x0.x, P0); P1 = fmaf(wx1[0], x0.x, P1);
        P0 = fmaf(wx0[1], x0.y, P0); P1 = fmaf(wx1[1], x0.y, P1);
        P0 = fmaf(wx0[2], x0.z, P0); P1 = fmaf(wx1[2], x0.z, P1);
        P0 = fmaf(wx0[3], x0.w, P0); P1 = fmaf(wx1[3], x0.w, P1);
        float t0 = fmaf(outS, sig2f(P0), outB);
        float t1 = sig2f(P1);
        float iv, gv, fv, ov;
        bcast_halves(a, t0, iv, gv);
        bcast_halves(a, t1, fv, ov);
        (void)fv;
        c1 = iv * gv;
        const float h1n = ov * fmaf(2.0f, sig2f(M2 * c1), -1.0f);   // h1(0)
#pragma unroll
        for (int k = 0; k < HH; ++k) hs1[k] = lanebc(h1n, k);
    }
    v4f xc = xp[(T > 1) ? 1 : 0];                          // x(1)

    // Invariant at iter t: hs1 = h1(t), hs2 = h2(t-1), c1 = c1(t),
    // c2 = c2(t-1), xc = x(t+1).  (Rotated loop: computes L2(t) + L1(t+1).)
    for (int t = 0; t < T; ++t) {
        const v4f xn = xp[(t + 2 < T) ? (t + 2) : (T - 1)];

        // ===== 6 independent scalar FMA chains, SGPR h-operands =====
        // A0/A1 : Whh1@h1 + Wih1@x(t+1) + bias1   (L1 for t+1, rows r0/r1)
        // Bi0/1 : Wih2@h1 + bias2                 (L2 input path)
        // Bh0/1 : Whh2@h2                         (L2 recurrent path)
        float A0 = bias1_0, A1 = bias1_1;
        float Bi0 = bias2_0, Bi1 = bias2_1;
        float Bh0 = 0.0f, Bh1 = 0.0f;

        A0 = fmaf(wx0[0], xc.x, A0); A1 = fmaf(wx1[0], xc.x, A1);
        A0 = fmaf(wx0[1], xc.y, A0); A1 = fmaf(wx1[1], xc.y, A1);
        A0 = fmaf(wx0[2], xc.z, A0); A1 = fmaf(wx1[2], xc.z, A1);
        A0 = fmaf(wx0[3], xc.w, A0); A1 = fmaf(wx1[3], xc.w, A1);

#pragma unroll
        for (int k = 0; k < HH; ++k) {
            A0  = fmaf(wh1a[k], hs1[k], A0);
            A1  = fmaf(wh1b[k], hs1[k], A1);
            Bi0 = fmaf(wi2a[k], hs1[k], Bi0);
            Bi1 = fmaf(wi2b[k], hs1[k], Bi1);
            Bh0 = fmaf(wh2a[k], hs2[k], Bh0);
            Bh1 = fmaf(wh2b[k], hs2[k], Bh1);
        }

        // ===== two independent activation/update tails =====
        const float Bv0 = Bi0 + Bh0;
        const float Bv1 = Bi1 + Bh1;

        float b0 = fmaf(outS, sig2f(Bv0), outB);   // L2: i/g
        float b1 = sig2f(Bv1);                     // L2: f/o
        float a0v = fmaf(outS, sig2f(A0), outB);   // L1(t+1): i/g
        float a1v = sig2f(A1);                     // L1(t+1): f/o

        float iv2, gv2, fv2, ov2, iv1, gv1, fv1, ov1;
        bcast_halves(a, b0, iv2, gv2);
        bcast_halves(a, b1, fv2, ov2);
        bcast_halves(a, a0v, iv1, gv1);
        bcast_halves(a, a1v, fv1, ov1);

        c2 = fmaf(fv2, c2, iv2 * gv2);
        c1 = fmaf(fv1, c1, iv1 * gv1);
        const float h2n = ov2 * fmaf(2.0f, sig2f(M2 * c2), -1.0f);  // h2(t)
        const float h1n = ov1 * fmaf(2.0f, sig2f(M2 * c1), -1.0f);  // h1(t+1)

        // ===== refill SGPR broadcasts (independent; hide under head) =====
#pragma unroll
        for (int k = 0; k < HH; ++k) hs2[k] = lanebc(h2n, k);
#pragma unroll
        for (int k = 0; k < HH; ++k) hs1[k] = lanebc(h1n, k);

        // ===== head: out(t) = Wlin @ h2(t) + b — VALU-pipe DPP reduce =====
        const float rx = half_reduce(wl0 * h2n);   // 0 on pad lanes
        const float ry = half_reduce(wl1 * h2n);
        if ((tid & 31) == 31) {                    // lane31 (a=0), lane63 (a=1)
            op[2 * t] = (v2f){rx + bl0, ry + bl1};
        }
        xc = xn;
    }
}

extern "C" void kernel_launch(void* const* d_in, const int* in_sizes, int n_in,
                              void* d_out, int out_size, void* d_ws, size_t ws_size,
                              hipStream_t stream)
{
    const float* x    = (const float*)d_in[0];
    const float* Wih1 = (const float*)d_in[1];
    const float* bih1 = (const float*)d_in[2];
    const float* Whh1 = (const float*)d_in[3];
    const float* bhh1 = (const float*)d_in[4];
    const float* Wih2 = (const float*)d_in[5];
    const float* bih2 = (const float*)d_in[6];
    const float* Whh2 = (const float*)d_in[7];
    const float* bhh2 = (const float*)d_in[8];
    const float* Wlin = (const float*)d_in[9];
    const float* blin = (const float*)d_in[10];
    float* out = (float*)d_out;

    const int T = 1024;
    const int B = in_sizes[0] / (T * DIN);   // 2048

    hipLaunchKernelGGL(lstm2_kernel, dim3(B), dim3(64), 0, stream,
                       x, Wih1, bih1, Whh1, bhh1, Wih2, bih2, Whh2, bhh2,
                       Wlin, blin, out, T);
}

// Round 7
// 1013.535 us; speedup vs baseline: 1.1596x; 1.1596x over previous
//
#include <hip/hip_runtime.h>

typedef float f32x4 __attribute__((ext_vector_type(4)));
typedef float v4f  __attribute__((ext_vector_type(4)));
typedef _Float16 half8 __attribute__((ext_vector_type(8)));
typedef unsigned int u32;
typedef u32 u32x4 __attribute__((ext_vector_type(4)));

#define HH 30
#define DIN 4
#define DOUT 4
#define NB 16      // batch elements per block
#define L2E 1.44269504088896340736f

#if __has_builtin(__builtin_amdgcn_exp2f)
#define EXP2F(v) __builtin_amdgcn_exp2f(v)
#else
#define EXP2F(v) exp2f(v)
#endif

// Pre-scaled sigmoid: -log2e (g rows: -2*log2e) folded into W and bias.
__device__ __forceinline__ float sig2f(float v) {
    return __builtin_amdgcn_rcpf(1.0f + EXP2F(v));
}

__device__ __forceinline__ f32x4 MF(half8 a, half8 b, f32x4 c) {
    return __builtin_amdgcn_mfma_f32_16x16x32_f16(a, b, c, 0, 0, 0);
}

union F8 { half8 h; _Float16 e[8]; u32 w[4]; };

// f32 -> packed u32: hi f16 in low16, residual-lo f16 in high16.
__device__ __forceinline__ u32 packh(float v) {
    _Float16 hi = (_Float16)v;
    _Float16 lo = (_Float16)(v - (float)hi);
    union { _Float16 h; unsigned short s; } A, B;
    A.h = hi; B.h = lo;
    return (u32)A.s | ((u32)B.s << 16);
}

// Build hi/lo B-frags from 8 packed u32 (d0: k=4p..4p+3, d1: k=16+4p..+3).
// half8 elem e holds k = 16*(e>>2) + 4p + (e&3).
__device__ __forceinline__ void mkfrags(u32x4 d0, u32x4 d1, half8& hi, half8& lo) {
    F8 H, L;
    H.w[0] = (d0[0] & 0xffffu) | (d0[1] << 16);
    H.w[1] = (d0[2] & 0xffffu) | (d0[3] << 16);
    H.w[2] = (d1[0] & 0xffffu) | (d1[1] << 16);
    H.w[3] = (d1[2] & 0xffffu) | (d1[3] << 16);
    L.w[0] = (d0[0] >> 16) | (d0[1] & 0xffff0000u);
    L.w[1] = (d0[2] >> 16) | (d0[3] & 0xffff0000u);
    L.w[2] = (d1[0] >> 16) | (d1[1] & 0xffff0000u);
    L.w[3] = (d1[2] >> 16) | (d1[3] & 0xffff0000u);
    hi = H.h; lo = L.h;
}

// MFMA-batched 2-layer LSTM. One block = 4 waves = 16 batch elements.
// Gate rows packed interleaved: packed row R = 4q + g (g: 0=i,1=f,2=g,3=o),
// so a C-frag lane (q = 4rt + p, col n = elem) holds all 4 gates of one
// (q, elem) -> lane-local c/h update, no cross-lane gate exchange.
// Weights: f16 hi/lo split, 3 MFMAs per product (hi*hi, hi*lo, lo*hi),
// f32 accumulation; -log2e (g rows -2log2e) folded into W & bias.
// h broadcast per step through LDS ([n][k] u32 = hi16|lo16), double-buffered,
// ONE __syncthreads per step. Rotated loop: iter t = G2(t) + G1(t+1), both
// consuming Bh1(t). Wave w owns row-tiles {2w, 2w+1}; wave 3 also does the
// Wlin head (out rows 0-3 live in p==0 lanes -> dwordx4 store per elem).
__global__ __launch_bounds__(256)
void lstm2_kernel(const float* __restrict__ x,
                  const float* __restrict__ Wih1, const float* __restrict__ bih1,
                  const float* __restrict__ Whh1, const float* __restrict__ bhh1,
                  const float* __restrict__ Wih2, const float* __restrict__ bih2,
                  const float* __restrict__ Whh2, const float* __restrict__ bhh2,
                  const float* __restrict__ Wlin, const float* __restrict__ blin,
                  float* __restrict__ out, int T)
{
    const int tid = threadIdx.x;
    const int w = tid >> 6;        // wave 0..3
    const int l = tid & 63;        // lane
    const int n = l & 15;          // elem col / A-row-in-tile
    const int p = l >> 4;          // quad index (k-group / C-row-group)
    const int b0 = blockIdx.x * NB;
    const float M2 = -2.0f * L2E;  // tanh(c) = 2*sig2f(M2*c)-1

    __shared__ __align__(16) u32 hlds[2][2][16][36];  // [buf][layer][n][k]

    // ---------- weight A-frags (once; amortized over T steps) ----------
    const int gA = n & 3;                       // gate of this A row
    const float scA = (gA == 2) ? -2.0f * L2E : -L2E;

    half8 a1h_h[2], a1h_l[2];    // Whh1   (L1, h1-ktile)
    half8 a1x_h[2], a1x_l[2];    // Wih1   (L1, x-ktile)
    half8 a2i_h[2], a2i_l[2];    // Wih2   (L2, h1-ktile)
    half8 a2h_h[2], a2h_l[2];    // Whh2   (L2, h2-ktile)
    f32x4 bias1f[2], bias2f[2];

#pragma unroll
    for (int ri = 0; ri < 2; ++ri) {
        const int rt = 2 * w + ri;
        const int qA = 4 * rt + (n >> 2);       // h-row index of this A row
        F8 Hh, Hl, Xh, Xl, Ih, Il, Rh, Rl;
#pragma unroll
        for (int e = 0; e < 8; ++e) {
            const int k = 16 * (e >> 2) + 4 * p + (e & 3);
            float v; _Float16 t16;
            v = (qA < HH && k < HH) ? Whh1[(gA * HH + qA) * HH + k] * scA : 0.0f;
            t16 = (_Float16)v; Hh.e[e] = t16; Hl.e[e] = (_Float16)(v - (float)t16);
            v = (qA < HH && k < DIN) ? Wih1[(gA * HH + qA) * DIN + k] * scA : 0.0f;
            t16 = (_Float16)v; Xh.e[e] = t16; Xl.e[e] = (_Float16)(v - (float)t16);
            v = (qA < HH && k < HH) ? Wih2[(gA * HH + qA) * HH + k] * scA : 0.0f;
            t16 = (_Float16)v; Ih.e[e] = t16; Il.e[e] = (_Float16)(v - (float)t16);
            v = (qA < HH && k < HH) ? Whh2[(gA * HH + qA) * HH + k] * scA : 0.0f;
            t16 = (_Float16)v; Rh.e[e] = t16; Rl.e[e] = (_Float16)(v - (float)t16);
        }
        a1h_h[ri] = Hh.h; a1h_l[ri] = Hl.h;
        a1x_h[ri] = Xh.h; a1x_l[ri] = Xl.h;
        a2i_h[ri] = Ih.h; a2i_l[ri] = Il.h;
        a2h_h[ri] = Rh.h; a2h_l[ri] = Rl.h;

        const int qC = 4 * rt + p;              // C-frag h-row of this lane
        f32x4 b1, b2;
#pragma unroll
        for (int r = 0; r < 4; ++r) {
            const float scr = (r == 2) ? -2.0f * L2E : -L2E;
            b1[r] = (qC < HH) ? (bih1[r * HH + qC] + bhh1[r * HH + qC]) * scr : 0.0f;
            b2[r] = (qC < HH) ? (bih2[r * HH + qC] + bhh2[r * HH + qC]) * scr : 0.0f;
        }
        bias1f[ri] = b1; bias2f[ri] = b2;
    }

    // head frags (all waves build; only wave 3 uses). Wlin rows NOT interleaved.
    half8 alin_h, alin_l;
    f32x4 blinf;
    {
        F8 Lh, Ll;
#pragma unroll
        for (int e = 0; e < 8; ++e) {
            const int k = 16 * (e >> 2) + 4 * p + (e & 3);
            float v = (n < DOUT && k < HH) ? Wlin[n * HH + k] : 0.0f;
            _Float16 t16 = (_Float16)v;
            Lh.e[e] = t16; Ll.e[e] = (_Float16)(v - (float)t16);
        }
        alin_h = Lh.h; alin_l = Ll.h;
#pragma unroll
        for (int r = 0; r < 4; ++r)
            blinf[r] = (p == 0) ? blin[r] : 0.0f;
    }

    float c1[2] = {0.0f, 0.0f}, c2[2] = {0.0f, 0.0f};
    half8 bh1_h, bh1_l, bh2_h, bh2_l;

    const v4f* xp = reinterpret_cast<const v4f*>(x) + (size_t)(b0 + n) * T;
    v4f xc = xp[0];

    // ---------- prologue: L1(0) with h1(-1)=0 ----------
    {
        F8 XH, XL;
#pragma unroll
        for (int e = 0; e < 8; ++e) { XH.e[e] = (_Float16)0.0f; XL.e[e] = (_Float16)0.0f; }
        if (p == 0) {
#pragma unroll
            for (int e = 0; e < 4; ++e) {
                _Float16 t16 = (_Float16)xc[e];
                XH.e[e] = t16; XL.e[e] = (_Float16)(xc[e] - (float)t16);
            }
        }
        const half8 bx_h = XH.h, bx_l = XL.h;
#pragma unroll
        for (int ri = 0; ri < 2; ++ri) {
            f32x4 g1 = bias1f[ri];
            g1 = MF(a1x_h[ri], bx_h, g1);
            g1 = MF(a1x_h[ri], bx_l, g1);
            g1 = MF(a1x_l[ri], bx_h, g1);
            const float iv = sig2f(g1[0]);
            const float fv = sig2f(g1[1]);
            const float gg = fmaf(2.0f, sig2f(g1[2]), -1.0f);
            const float ov = sig2f(g1[3]);
            c1[ri] = fmaf(fv, c1[ri], iv * gg);
            const float h1n = ov * fmaf(2.0f, sig2f(M2 * c1[ri]), -1.0f);
            const int q = 8 * w + 4 * ri + p;
            hlds[0][0][n][q] = (q < HH) ? packh(h1n) : 0u;
            hlds[0][1][n][q] = 0u;                    // h2(-1) = 0
        }
    }
    __syncthreads();
    {
        const u32x4* r0 = reinterpret_cast<const u32x4*>(&hlds[0][0][n][4 * p]);
        const u32x4* r1 = reinterpret_cast<const u32x4*>(&hlds[0][0][n][16 + 4 * p]);
        mkfrags(r0[0], r1[0], bh1_h, bh1_l);
        const u32x4* s0 = reinterpret_cast<const u32x4*>(&hlds[0][1][n][4 * p]);
        const u32x4* s1 = reinterpret_cast<const u32x4*>(&hlds[0][1][n][16 + 4 * p]);
        mkfrags(s0[0], s1[0], bh2_h, bh2_l);
    }
    xc = xp[(T > 1) ? 1 : 0];                         // x(1)

    // Invariant at iter t: bh1 = h1(t), bh2 = h2(t-1), c1 = c1(t),
    // c2 = c2(t-1), xc = x(t+1).
    for (int t = 0; t < T; ++t) {
        const v4f xn = xp[(t + 2 < T) ? (t + 2) : (T - 1)];

        // Bx(t+1)
        F8 XH, XL;
#pragma unroll
        for (int e = 0; e < 8; ++e) { XH.e[e] = (_Float16)0.0f; XL.e[e] = (_Float16)0.0f; }
        if (p == 0) {
#pragma unroll
            for (int e = 0; e < 4; ++e) {
                _Float16 t16 = (_Float16)xc[e];
                XH.e[e] = t16; XL.e[e] = (_Float16)(xc[e] - (float)t16);
            }
        }
        const half8 bx_h = XH.h, bx_l = XL.h;

        const int bw = (t + 1) & 1;
#pragma unroll
        for (int ri = 0; ri < 2; ++ri) {
            // L2(t): Wih2 @ h1(t) + Whh2 @ h2(t-1) + bias2
            f32x4 g2 = bias2f[ri];
            g2 = MF(a2i_h[ri], bh1_h, g2);
            g2 = MF(a2i_h[ri], bh1_l, g2);
            g2 = MF(a2i_l[ri], bh1_h, g2);
            g2 = MF(a2h_h[ri], bh2_h, g2);
            g2 = MF(a2h_h[ri], bh2_l, g2);
            g2 = MF(a2h_l[ri], bh2_h, g2);
            // L1(t+1): Whh1 @ h1(t) + Wih1 @ x(t+1) + bias1
            f32x4 g1 = bias1f[ri];
            g1 = MF(a1h_h[ri], bh1_h, g1);
            g1 = MF(a1h_h[ri], bh1_l, g1);
            g1 = MF(a1h_l[ri], bh1_h, g1);
            g1 = MF(a1x_h[ri], bx_h, g1);
            g1 = MF(a1x_h[ri], bx_l, g1);
            g1 = MF(a1x_l[ri], bx_h, g1);

            // lane-local activations: regs r = i,f,g,o of (q, elem n)
            const float iv2 = sig2f(g2[0]);
            const float fv2 = sig2f(g2[1]);
            const float gg2 = fmaf(2.0f, sig2f(g2[2]), -1.0f);
            const float ov2 = sig2f(g2[3]);
            c2[ri] = fmaf(fv2, c2[ri], iv2 * gg2);
            const float h2n = ov2 * fmaf(2.0f, sig2f(M2 * c2[ri]), -1.0f);

            const float iv1 = sig2f(g1[0]);
            const float fv1 = sig2f(g1[1]);
            const float gg1 = fmaf(2.0f, sig2f(g1[2]), -1.0f);
            const float ov1 = sig2f(g1[3]);
            c1[ri] = fmaf(fv1, c1[ri], iv1 * gg1);
            const float h1n = ov1 * fmaf(2.0f, sig2f(M2 * c1[ri]), -1.0f);

            const int q = 8 * w + 4 * ri + p;
            hlds[bw][0][n][q] = (q < HH) ? packh(h1n) : 0u;   // h1(t+1)
            hlds[bw][1][n][q] = (q < HH) ? packh(h2n) : 0u;   // h2(t)
        }
        __syncthreads();
        {
            const u32x4* r0 = reinterpret_cast<const u32x4*>(&hlds[bw][0][n][4 * p]);
            const u32x4* r1 = reinterpret_cast<const u32x4*>(&hlds[bw][0][n][16 + 4 * p]);
            mkfrags(r0[0], r1[0], bh1_h, bh1_l);
            const u32x4* s0 = reinterpret_cast<const u32x4*>(&hlds[bw][1][n][4 * p]);
            const u32x4* s1 = reinterpret_cast<const u32x4*>(&hlds[bw][1][n][16 + 4 * p]);
            mkfrags(s0[0], s1[0], bh2_h, bh2_l);
        }

        // head: out(t) = Wlin @ h2(t) + blin (wave 3; rows 0-3 on p==0 lanes)
        if (w == 3) {
            f32x4 oh = blinf;
            oh = MF(alin_h, bh2_h, oh);
            oh = MF(alin_h, bh2_l, oh);
            oh = MF(alin_l, bh2_h, oh);
            if (p == 0) {
                v4f ov;
                ov.x = oh[0]; ov.y = oh[1]; ov.z = oh[2]; ov.w = oh[3];
                *reinterpret_cast<v4f*>(out + (((size_t)(b0 + n)) * T + t) * DOUT) = ov;
            }
        }
        xc = xn;
    }
}

extern "C" void kernel_launch(void* const* d_in, const int* in_sizes, int n_in,
                              void* d_out, int out_size, void* d_ws, size_t ws_size,
                              hipStream_t stream)
{
    const float* x    = (const float*)d_in[0];
    const float* Wih1 = (const float*)d_in[1];
    const float* bih1 = (const float*)d_in[2];
    const float* Whh1 = (const float*)d_in[3];
    const float* bhh1 = (const float*)d_in[4];
    const float* Wih2 = (const float*)d_in[5];
    const float* bih2 = (const float*)d_in[6];
    const float* Whh2 = (const float*)d_in[7];
    const float* bhh2 = (const float*)d_in[8];
    const float* Wlin = (const float*)d_in[9];
    const float* blin = (const float*)d_in[10];
    float* out = (float*)d_out;

    const int T = 1024;
    const int B = in_sizes[0] / (T * DIN);   // 2048

    hipLaunchKernelGGL(lstm2_kernel, dim3(B / NB), dim3(256), 0, stream,
                       x, Wih1, bih1, Whh1, bhh1, Wih2, bih2, Whh2, bhh2,
                       Wlin, blin, out, T);
}

// Round 8
// 917.009 us; speedup vs baseline: 1.2817x; 1.1053x over previous
//
#include <hip/hip_runtime.h>

typedef float f32x4 __attribute__((ext_vector_type(4)));
typedef float v4f  __attribute__((ext_vector_type(4)));
typedef _Float16 half8 __attribute__((ext_vector_type(8)));
typedef unsigned int u32;
typedef unsigned short u16;

#define HH 30
#define DIN 4
#define DOUT 4
#define NB 16      // batch elements per block
#define L2E 1.44269504088896340736f

#if __has_builtin(__builtin_amdgcn_exp2f)
#define EXP2F(v) __builtin_amdgcn_exp2f(v)
#else
#define EXP2F(v) exp2f(v)
#endif

// Pre-scaled sigmoid: -log2e (g rows: -2*log2e) folded into W and bias.
__device__ __forceinline__ float sig2f(float v) {
    return __builtin_amdgcn_rcpf(1.0f + EXP2F(v));
}

__device__ __forceinline__ f32x4 MF(half8 a, half8 b, f32x4 c) {
    return __builtin_amdgcn_mfma_f32_16x16x32_f16(a, b, c, 0, 0, 0);
}

union F8 { half8 h; _Float16 e[8]; u32 w[4]; };
union HU { _Float16 h; u16 s; };

// Workgroup barrier with LGKM-only drain: DS writes must be visible before
// the barrier, but outstanding GLOBAL loads (x prefetch) need NOT be drained
// (cross-wave correctness only involves LDS). This removes the vmcnt(0)
// drain __syncthreads would insert — the per-step HBM latency exposure.
__device__ __forceinline__ void lds_barrier() {
    __builtin_amdgcn_sched_barrier(0);
    asm volatile("s_waitcnt lgkmcnt(0)" ::: "memory");
    __builtin_amdgcn_sched_barrier(0);
    __builtin_amdgcn_s_barrier();
    __builtin_amdgcn_sched_barrier(0);
}

// MFMA-batched 2-layer LSTM. One block = 4 waves = 16 batch elements.
// Gate rows interleaved (packed row R = 4q + g) -> each C-frag lane holds all
// 4 gates of one (h-index q, elem n): lane-local c/h update, no exchange.
// Weights f16 hi/lo split, 3 MFMAs per product (hh, hl, lh), f32 accum;
// -log2e (g rows -2log2e) folded into W & bias.
//
// THIS ROUND (latency cuts; structure unchanged):
//  * lds_barrier(): lgkm-only drain (no vmcnt) -> x-load latency off the path
//  * x prefetch issued AFTER the barrier section, consumed next iter (~full
//    step of slack before its use-site vmcnt wait)
//  * h transported through LDS in FRAG LAYOUT: 4 u16 arrays [n][40]
//    (h1hi,h1lo,h2hi,h2lo), value for k at [n][((k&15)>>2)*8+(k>>4)*4+(k&3)]
//    -> B-frags are 4 plain ds_read_b128, ZERO repack VALU (mkfrags deleted).
//    Stride 40 u16 (80 B) -> read banks 2-way max (free).
//  * MFMA accumulator chains split 6 -> 3+3 (+1 f32x4 add)
__global__ __launch_bounds__(256)
void lstm2_kernel(const float* __restrict__ x,
                  const float* __restrict__ Wih1, const float* __restrict__ bih1,
                  const float* __restrict__ Whh1, const float* __restrict__ bhh1,
                  const float* __restrict__ Wih2, const float* __restrict__ bih2,
                  const float* __restrict__ Whh2, const float* __restrict__ bhh2,
                  const float* __restrict__ Wlin, const float* __restrict__ blin,
                  float* __restrict__ out, int T)
{
    const int tid = threadIdx.x;
    const int w = tid >> 6;        // wave 0..3
    const int l = tid & 63;        // lane
    const int n = l & 15;          // elem col / A-row-in-tile
    const int p = l >> 4;          // quad index (k-group / C-row-group)
    const int b0 = blockIdx.x * NB;
    const float M2 = -2.0f * L2E;  // tanh(c) = 2*sig2f(M2*c)-1

    // [buf][arr: 0=h1hi 1=h1lo 2=h2hi 3=h2lo][n][pos], stride 40 u16 = 80 B
    __shared__ __align__(16) u16 lds[2][4][16][40];

    // ---- zero-init LDS (pads + h2(-1)=0), then sync ----
    {
        u32* z = reinterpret_cast<u32*>(&lds[0][0][0][0]);
        const int tot = 2 * 4 * 16 * 40 / 2;   // u32 count
        for (int i = tid; i < tot; i += 256) z[i] = 0u;
    }

    // ---------- weight A-frags (once; amortized over T steps) ----------
    const int gA = n & 3;                       // gate of this A row
    const float scA = (gA == 2) ? -2.0f * L2E : -L2E;

    half8 a1h_h[2], a1h_l[2];    // Whh1   (L1, h1-ktile)
    half8 a1x_h[2], a1x_l[2];    // Wih1   (L1, x-ktile)
    half8 a2i_h[2], a2i_l[2];    // Wih2   (L2, h1-ktile)
    half8 a2h_h[2], a2h_l[2];    // Whh2   (L2, h2-ktile)
    f32x4 bias1f[2], bias2f[2];

#pragma unroll
    for (int ri = 0; ri < 2; ++ri) {
        const int rt = 2 * w + ri;
        const int qA = 4 * rt + (n >> 2);       // h-row index of this A row
        F8 Hh, Hl, Xh, Xl, Ih, Il, Rh, Rl;
#pragma unroll
        for (int e = 0; e < 8; ++e) {
            const int k = 16 * (e >> 2) + 4 * p + (e & 3);
            float v; _Float16 t16;
            v = (qA < HH && k < HH) ? Whh1[(gA * HH + qA) * HH + k] * scA : 0.0f;
            t16 = (_Float16)v; Hh.e[e] = t16; Hl.e[e] = (_Float16)(v - (float)t16);
            v = (qA < HH && k < DIN) ? Wih1[(gA * HH + qA) * DIN + k] * scA : 0.0f;
            t16 = (_Float16)v; Xh.e[e] = t16; Xl.e[e] = (_Float16)(v - (float)t16);
            v = (qA < HH && k < HH) ? Wih2[(gA * HH + qA) * HH + k] * scA : 0.0f;
            t16 = (_Float16)v; Ih.e[e] = t16; Il.e[e] = (_Float16)(v - (float)t16);
            v = (qA < HH && k < HH) ? Whh2[(gA * HH + qA) * HH + k] * scA : 0.0f;
            t16 = (_Float16)v; Rh.e[e] = t16; Rl.e[e] = (_Float16)(v - (float)t16);
        }
        a1h_h[ri] = Hh.h; a1h_l[ri] = Hl.h;
        a1x_h[ri] = Xh.h; a1x_l[ri] = Xl.h;
        a2i_h[ri] = Ih.h; a2i_l[ri] = Il.h;
        a2h_h[ri] = Rh.h; a2h_l[ri] = Rl.h;

        const int qC = 4 * rt + p;              // C-frag h-row of this lane
        f32x4 b1, b2;
#pragma unroll
        for (int r = 0; r < 4; ++r) {
            const float scr = (r == 2) ? -2.0f * L2E : -L2E;
            b1[r] = (qC < HH) ? (bih1[r * HH + qC] + bhh1[r * HH + qC]) * scr : 0.0f;
            b2[r] = (qC < HH) ? (bih2[r * HH + qC] + bhh2[r * HH + qC]) * scr : 0.0f;
        }
        bias1f[ri] = b1; bias2f[ri] = b2;
    }

    // head frags (all waves build; only wave 3 uses). Wlin rows NOT interleaved.
    half8 alin_h, alin_l;
    f32x4 blinf;
    {
        F8 Lh, Ll;
#pragma unroll
        for (int e = 0; e < 8; ++e) {
            const int k = 16 * (e >> 2) + 4 * p + (e & 3);
            float v = (n < DOUT && k < HH) ? Wlin[n * HH + k] : 0.0f;
            _Float16 t16 = (_Float16)v;
            Lh.e[e] = t16; Ll.e[e] = (_Float16)(v - (float)t16);
        }
        alin_h = Lh.h; alin_l = Ll.h;
#pragma unroll
        for (int r = 0; r < 4; ++r)
            blinf[r] = (p == 0) ? blin[r] : 0.0f;
    }

    float c1[2] = {0.0f, 0.0f}, c2[2] = {0.0f, 0.0f};
    half8 bh1_h, bh1_l, bh2_h, bh2_l;

    const v4f* xp = reinterpret_cast<const v4f*>(x) + (size_t)(b0 + n) * T;
    v4f xc = xp[0];

    __syncthreads();   // zero-init visible before prologue h-writes

    // ---------- prologue: L1(0) with h1(-1)=0 ----------
    {
        F8 XH, XL;
#pragma unroll
        for (int e = 0; e < 8; ++e) { XH.e[e] = (_Float16)0.0f; XL.e[e] = (_Float16)0.0f; }
        if (p == 0) {
#pragma unroll
            for (int e = 0; e < 4; ++e) {
                _Float16 t16 = (_Float16)xc[e];
                XH.e[e] = t16; XL.e[e] = (_Float16)(xc[e] - (float)t16);
            }
        }
        const half8 bx_h = XH.h, bx_l = XL.h;
#pragma unroll
        for (int ri = 0; ri < 2; ++ri) {
            f32x4 g1 = bias1f[ri];
            g1 = MF(a1x_h[ri], bx_h, g1);
            g1 = MF(a1x_h[ri], bx_l, g1);
            g1 = MF(a1x_l[ri], bx_h, g1);
            const float iv = sig2f(g1[0]);
            const float fv = sig2f(g1[1]);
            const float gg = fmaf(2.0f, sig2f(g1[2]), -1.0f);
            const float ov = sig2f(g1[3]);
            c1[ri] = fmaf(fv, c1[ri], iv * gg);
            const float h1n = ov * fmaf(2.0f, sig2f(M2 * c1[ri]), -1.0f);
            const int kq = 8 * w + 4 * ri + p;
            const int pos = ((kq & 15) >> 2) * 8 + (kq >> 4) * 4 + (kq & 3);
            HU hi, lo;
            hi.h = (_Float16)h1n;
            lo.h = (_Float16)(h1n - (float)hi.h);
            lds[0][0][n][pos] = (kq < HH) ? hi.s : (u16)0;
            lds[0][1][n][pos] = (kq < HH) ? lo.s : (u16)0;
            // h2(-1) arrays stay zero from memset
        }
    }
    __syncthreads();
    {
        bh1_h = *reinterpret_cast<const half8*>(&lds[0][0][n][8 * p]);
        bh1_l = *reinterpret_cast<const half8*>(&lds[0][1][n][8 * p]);
        bh2_h = *reinterpret_cast<const half8*>(&lds[0][2][n][8 * p]);
        bh2_l = *reinterpret_cast<const half8*>(&lds[0][3][n][8 * p]);
    }
    xc = xp[(T > 1) ? 1 : 0];                         // x(1)

    const f32x4 zf = {0.0f, 0.0f, 0.0f, 0.0f};

    // Invariant at iter t: bh1 = h1(t), bh2 = h2(t-1), c1 = c1(t),
    // c2 = c2(t-1), xc = x(t+1).
    for (int t = 0; t < T; ++t) {
        // Bx(t+1) from xc (loaded last iter; natural use-site vmcnt wait
        // with ~a full step of slack — no barrier drain involved).
        F8 XH, XL;
#pragma unroll
        for (int e = 0; e < 8; ++e) { XH.e[e] = (_Float16)0.0f; XL.e[e] = (_Float16)0.0f; }
        if (p == 0) {
#pragma unroll
            for (int e = 0; e < 4; ++e) {
                _Float16 t16 = (_Float16)xc[e];
                XH.e[e] = t16; XL.e[e] = (_Float16)(xc[e] - (float)t16);
            }
        }
        const half8 bx_h = XH.h, bx_l = XL.h;

        const int bw = (t + 1) & 1;
#pragma unroll
        for (int ri = 0; ri < 2; ++ri) {
            // L2(t): split chains 3+3
            f32x4 g2a = bias2f[ri];
            g2a = MF(a2i_h[ri], bh1_h, g2a);
            g2a = MF(a2i_h[ri], bh1_l, g2a);
            g2a = MF(a2i_l[ri], bh1_h, g2a);
            f32x4 g2b = zf;
            g2b = MF(a2h_h[ri], bh2_h, g2b);
            g2b = MF(a2h_h[ri], bh2_l, g2b);
            g2b = MF(a2h_l[ri], bh2_h, g2b);
            const f32x4 g2 = g2a + g2b;
            // L1(t+1): split chains 3+3
            f32x4 g1a = bias1f[ri];
            g1a = MF(a1h_h[ri], bh1_h, g1a);
            g1a = MF(a1h_h[ri], bh1_l, g1a);
            g1a = MF(a1h_l[ri], bh1_h, g1a);
            f32x4 g1b = zf;
            g1b = MF(a1x_h[ri], bx_h, g1b);
            g1b = MF(a1x_h[ri], bx_l, g1b);
            g1b = MF(a1x_l[ri], bx_h, g1b);
            const f32x4 g1 = g1a + g1b;

            // lane-local activations (i,f,g,o of (q, elem n))
            const float iv2 = sig2f(g2[0]);
            const float fv2 = sig2f(g2[1]);
            const float gg2 = fmaf(2.0f, sig2f(g2[2]), -1.0f);
            const float ov2 = sig2f(g2[3]);
            c2[ri] = fmaf(fv2, c2[ri], iv2 * gg2);
            const float h2n = ov2 * fmaf(2.0f, sig2f(M2 * c2[ri]), -1.0f);

            const float iv1 = sig2f(g1[0]);
            const float fv1 = sig2f(g1[1]);
            const float gg1 = fmaf(2.0f, sig2f(g1[2]), -1.0f);
            const float ov1 = sig2f(g1[3]);
            c1[ri] = fmaf(fv1, c1[ri], iv1 * gg1);
            const float h1n = ov1 * fmaf(2.0f, sig2f(M2 * c1[ri]), -1.0f);

            // frag-layout stores: value k=q at [n][((q&15)>>2)*8+(q>>4)*4+(q&3)]
            const int kq = 8 * w + 4 * ri + p;
            const int pos = ((kq & 15) >> 2) * 8 + (kq >> 4) * 4 + (kq & 3);
            HU h1hi, h1lo, h2hi, h2lo;
            h1hi.h = (_Float16)h1n;
            h1lo.h = (_Float16)(h1n - (float)h1hi.h);
            h2hi.h = (_Float16)h2n;
            h2lo.h = (_Float16)(h2n - (float)h2hi.h);
            const bool ok = (kq < HH);
            lds[bw][0][n][pos] = ok ? h1hi.s : (u16)0;   // h1(t+1)
            lds[bw][1][n][pos] = ok ? h1lo.s : (u16)0;
            lds[bw][2][n][pos] = ok ? h2hi.s : (u16)0;   // h2(t)
            lds[bw][3][n][pos] = ok ? h2lo.s : (u16)0;
        }

        lds_barrier();   // lgkm-only drain + s_barrier (no vmcnt)

        bh1_h = *reinterpret_cast<const half8*>(&lds[bw][0][n][8 * p]);
        bh1_l = *reinterpret_cast<const half8*>(&lds[bw][1][n][8 * p]);
        bh2_h = *reinterpret_cast<const half8*>(&lds[bw][2][n][8 * p]);
        bh2_l = *reinterpret_cast<const half8*>(&lds[bw][3][n][8 * p]);

        // next-x prefetch issued HERE (post-barrier): consumed top of t+1;
        // its vmcnt wait lands a full step after issue.
        const v4f xn = xp[(t + 2 < T) ? (t + 2) : (T - 1)];

        // head: out(t) = Wlin @ h2(t) + blin (wave 3; rows 0-3 on p==0 lanes)
        if (w == 3) {
            f32x4 oh = blinf;
            oh = MF(alin_h, bh2_h, oh);
            oh = MF(alin_h, bh2_l, oh);
            oh = MF(alin_l, bh2_h, oh);
            if (p == 0) {
                v4f ov;
                ov.x = oh[0]; ov.y = oh[1]; ov.z = oh[2]; ov.w = oh[3];
                *reinterpret_cast<v4f*>(out + (((size_t)(b0 + n)) * T + t) * DOUT) = ov;
            }
        }
        xc = xn;
    }
}

extern "C" void kernel_launch(void* const* d_in, const int* in_sizes, int n_in,
                              void* d_out, int out_size, void* d_ws, size_t ws_size,
                              hipStream_t stream)
{
    const float* x    = (const float*)d_in[0];
    const float* Wih1 = (const float*)d_in[1];
    const float* bih1 = (const float*)d_in[2];
    const float* Whh1 = (const float*)d_in[3];
    const float* bhh1 = (const float*)d_in[4];
    const float* Wih2 = (const float*)d_in[5];
    const float* bih2 = (const float*)d_in[6];
    const float* Whh2 = (const float*)d_in[7];
    const float* bhh2 = (const float*)d_in[8];
    const float* Wlin = (const float*)d_in[9];
    const float* blin = (const float*)d_in[10];
    float* out = (float*)d_out;

    const int T = 1024;
    const int B = in_sizes[0] / (T * DIN);   // 2048

    hipLaunchKernelGGL(lstm2_kernel, dim3(B / NB), dim3(256), 0, stream,
                       x, Wih1, bih1, Whh1, bhh1, Wih2, bih2, Whh2, bhh2,
                       Wlin, blin, out, T);
}

// Round 9
// 761.995 us; speedup vs baseline: 1.5425x; 1.2034x over previous
//
#include <hip/hip_runtime.h>

typedef float f32x4 __attribute__((ext_vector_type(4)));
typedef float v4f  __attribute__((ext_vector_type(4)));
typedef _Float16 half8 __attribute__((ext_vector_type(8)));
typedef unsigned int u32;
typedef unsigned short u16;

#define HH 30
#define DIN 4
#define DOUT 4
#define NB 16      // batch elements per block
#define L2E 1.44269504088896340736f

#if __has_builtin(__builtin_amdgcn_exp2f)
#define EXP2F(v) __builtin_amdgcn_exp2f(v)
#else
#define EXP2F(v) exp2f(v)
#endif

// Pre-scaled sigmoid: -log2e (g rows: -2*log2e) folded into W and bias.
__device__ __forceinline__ float sig2f(float v) {
    return __builtin_amdgcn_rcpf(1.0f + EXP2F(v));
}

__device__ __forceinline__ f32x4 MF(half8 a, half8 b, f32x4 c) {
    return __builtin_amdgcn_mfma_f32_16x16x32_f16(a, b, c, 0, 0, 0);
}

union F8 { half8 h; _Float16 e[8]; u32 w[4]; };
union HU { _Float16 h; u16 s; };

// Workgroup barrier with LGKM-only drain (no vmcnt): cross-wave correctness
// only involves LDS; outstanding global x-prefetches stay in flight.
__device__ __forceinline__ void lds_barrier() {
    __builtin_amdgcn_sched_barrier(0);
    asm volatile("s_waitcnt lgkmcnt(0)" ::: "memory");
    __builtin_amdgcn_sched_barrier(0);
    __builtin_amdgcn_s_barrier();
    __builtin_amdgcn_sched_barrier(0);
}

// MFMA-batched 2-layer LSTM. One block = EIGHT waves = 16 batch elements.
// Gate rows interleaved (packed row R = 4q + g) -> each C-frag lane holds all
// 4 gates of one (h-index q, elem n): lane-local c/h update, no exchange.
// Wave w owns packed row-tile rt = w (rows 16w..16w+15, i.e. q = 4w..4w+3);
// per-wave work is HALF of R8's (12 MFMAs, one activation set) so 2 waves
// share each SIMD (TLP: one wave's DS/MFMA/trans latency hides under the
// other's issue). Weights f16 hi/lo split, 3 MFMAs per product, f32 accum;
// -log2e (g rows -2log2e) folded into W & bias.
// h transported through LDS in frag layout (4 u16 arrays [n][40], stride 80B,
// <=2-way banks). ONE lgkm-only barrier per step. Rotated loop: iter t does
// G2(t) + G1(t+1). x pipeline 2-deep: frags for x(t+1) ready, raw x(t+2) in
// flight; convert+issue-next post-barrier (full step of slack each).
__global__ __launch_bounds__(512)
void lstm2_kernel(const float* __restrict__ x,
                  const float* __restrict__ Wih1, const float* __restrict__ bih1,
                  const float* __restrict__ Whh1, const float* __restrict__ bhh1,
                  const float* __restrict__ Wih2, const float* __restrict__ bih2,
                  const float* __restrict__ Whh2, const float* __restrict__ bhh2,
                  const float* __restrict__ Wlin, const float* __restrict__ blin,
                  float* __restrict__ out, int T)
{
    const int tid = threadIdx.x;
    const int w = tid >> 6;        // wave 0..7
    const int l = tid & 63;        // lane
    const int n = l & 15;          // elem col / A-row-in-tile
    const int p = l >> 4;          // quad index (k-group / C-row-group)
    const int b0 = blockIdx.x * NB;
    const float M2 = -2.0f * L2E;  // tanh(c) = 2*sig2f(M2*c)-1

    // [buf][arr: 0=h1hi 1=h1lo 2=h2hi 3=h2lo][n][pos], stride 40 u16 = 80 B
    __shared__ __align__(16) u16 lds[2][4][16][40];

    // ---- zero-init LDS (pads + h2(-1)=0) ----
    {
        u32* z = reinterpret_cast<u32*>(&lds[0][0][0][0]);
        const int tot = 2 * 4 * 16 * 40 / 2;   // u32 count
        for (int i = tid; i < tot; i += 512) z[i] = 0u;
    }

    // ---------- weight A-frags (once; amortized over T steps) ----------
    const int gA = n & 3;                       // gate of this A row
    const float scA = (gA == 2) ? -2.0f * L2E : -L2E;
    const int qA = 4 * w + (n >> 2);            // h-row index of this A row

    half8 a1h_h, a1h_l;    // Whh1   (L1, h1-ktile)
    half8 a1x_h, a1x_l;    // Wih1   (L1, x-ktile)
    half8 a2i_h, a2i_l;    // Wih2   (L2, h1-ktile)
    half8 a2h_h, a2h_l;    // Whh2   (L2, h2-ktile)
    {
        F8 Hh, Hl, Xh, Xl, Ih, Il, Rh, Rl;
#pragma unroll
        for (int e = 0; e < 8; ++e) {
            const int k = 16 * (e >> 2) + 4 * p + (e & 3);
            float v; _Float16 t16;
            v = (qA < HH && k < HH) ? Whh1[(gA * HH + qA) * HH + k] * scA : 0.0f;
            t16 = (_Float16)v; Hh.e[e] = t16; Hl.e[e] = (_Float16)(v - (float)t16);
            v = (qA < HH && k < DIN) ? Wih1[(gA * HH + qA) * DIN + k] * scA : 0.0f;
            t16 = (_Float16)v; Xh.e[e] = t16; Xl.e[e] = (_Float16)(v - (float)t16);
            v = (qA < HH && k < HH) ? Wih2[(gA * HH + qA) * HH + k] * scA : 0.0f;
            t16 = (_Float16)v; Ih.e[e] = t16; Il.e[e] = (_Float16)(v - (float)t16);
            v = (qA < HH && k < HH) ? Whh2[(gA * HH + qA) * HH + k] * scA : 0.0f;
            t16 = (_Float16)v; Rh.e[e] = t16; Rl.e[e] = (_Float16)(v - (float)t16);
        }
        a1h_h = Hh.h; a1h_l = Hl.h;
        a1x_h = Xh.h; a1x_l = Xl.h;
        a2i_h = Ih.h; a2i_l = Il.h;
        a2h_h = Rh.h; a2h_l = Rl.h;
    }

    const int kq = 4 * w + p;                   // this lane's h-row (C frag)
    const bool okq = (kq < HH);
    const int pos = ((kq & 15) >> 2) * 8 + (kq >> 4) * 4 + (kq & 3);

    f32x4 bias1f, bias2f;
#pragma unroll
    for (int r = 0; r < 4; ++r) {
        const float scr = (r == 2) ? -2.0f * L2E : -L2E;
        bias1f[r] = okq ? (bih1[r * HH + kq] + bhh1[r * HH + kq]) * scr : 0.0f;
        bias2f[r] = okq ? (bih2[r * HH + kq] + bhh2[r * HH + kq]) * scr : 0.0f;
    }

    // head frags (wave 7 uses). Wlin rows NOT interleaved.
    half8 alin_h, alin_l;
    f32x4 blinf;
    {
        F8 Lh, Ll;
#pragma unroll
        for (int e = 0; e < 8; ++e) {
            const int k = 16 * (e >> 2) + 4 * p + (e & 3);
            float v = (n < DOUT && k < HH) ? Wlin[n * HH + k] : 0.0f;
            _Float16 t16 = (_Float16)v;
            Lh.e[e] = t16; Ll.e[e] = (_Float16)(v - (float)t16);
        }
        alin_h = Lh.h; alin_l = Ll.h;
#pragma unroll
        for (int r = 0; r < 4; ++r)
            blinf[r] = (p == 0) ? blin[r] : 0.0f;
    }

    float c1 = 0.0f, c2 = 0.0f;
    half8 bh1_h, bh1_l, bh2_h, bh2_l;

    const v4f* xp = reinterpret_cast<const v4f*>(x) + (size_t)(b0 + n) * T;
    const v4f x0 = xp[0];

    __syncthreads();   // zero-init visible before prologue h-writes

    // ---------- prologue: L1(0) with h1(-1)=0 ----------
    {
        F8 XH, XL;
#pragma unroll
        for (int e = 0; e < 8; ++e) { XH.e[e] = (_Float16)0.0f; XL.e[e] = (_Float16)0.0f; }
        if (p == 0) {
#pragma unroll
            for (int e = 0; e < 4; ++e) {
                _Float16 t16 = (_Float16)x0[e];
                XH.e[e] = t16; XL.e[e] = (_Float16)(x0[e] - (float)t16);
            }
        }
        f32x4 g1 = bias1f;
        g1 = MF(a1x_h, XH.h, g1);
        g1 = MF(a1x_h, XL.h, g1);
        g1 = MF(a1x_l, XH.h, g1);
        const float iv = sig2f(g1[0]);
        const float fv = sig2f(g1[1]);
        const float gg = fmaf(2.0f, sig2f(g1[2]), -1.0f);
        const float ov = sig2f(g1[3]);
        c1 = fmaf(fv, c1, iv * gg);
        const float h1n = ov * fmaf(2.0f, sig2f(M2 * c1), -1.0f);
        HU hi, lo;
        hi.h = (_Float16)h1n;
        lo.h = (_Float16)(h1n - (float)hi.h);
        lds[0][0][n][pos] = okq ? hi.s : (u16)0;
        lds[0][1][n][pos] = okq ? lo.s : (u16)0;
        // h2(-1) arrays stay zero from memset
    }
    __syncthreads();
    bh1_h = *reinterpret_cast<const half8*>(&lds[0][0][n][8 * p]);
    bh1_l = *reinterpret_cast<const half8*>(&lds[0][1][n][8 * p]);
    bh2_h = *reinterpret_cast<const half8*>(&lds[0][2][n][8 * p]);
    bh2_l = *reinterpret_cast<const half8*>(&lds[0][3][n][8 * p]);

    // ---- 2-deep x pipeline: bx = frags(x(1)) ready, xn = x(2) in flight ----
    half8 bx_h, bx_l;
    {
        const v4f x1 = xp[(T > 1) ? 1 : 0];
        F8 XH, XL;
#pragma unroll
        for (int e = 0; e < 8; ++e) { XH.e[e] = (_Float16)0.0f; XL.e[e] = (_Float16)0.0f; }
        if (p == 0) {
#pragma unroll
            for (int e = 0; e < 4; ++e) {
                _Float16 t16 = (_Float16)x1[e];
                XH.e[e] = t16; XL.e[e] = (_Float16)(x1[e] - (float)t16);
            }
        }
        bx_h = XH.h; bx_l = XL.h;
    }
    v4f xn = xp[(T > 2) ? 2 : (T - 1)];

    const f32x4 zf = {0.0f, 0.0f, 0.0f, 0.0f};

    // Invariant at iter t: bh1 = h1(t), bh2 = h2(t-1), c1 = c1(t),
    // c2 = c2(t-1), bx = frags(x(t+1)), xn = raw x(t+2).
    for (int t = 0; t < T; ++t) {
        // L2(t): split chains 3+3
        f32x4 g2a = bias2f;
        g2a = MF(a2i_h, bh1_h, g2a);
        g2a = MF(a2i_h, bh1_l, g2a);
        g2a = MF(a2i_l, bh1_h, g2a);
        f32x4 g2b = zf;
        g2b = MF(a2h_h, bh2_h, g2b);
        g2b = MF(a2h_h, bh2_l, g2b);
        g2b = MF(a2h_l, bh2_h, g2b);
        const f32x4 g2 = g2a + g2b;
        // L1(t+1): split chains 3+3
        f32x4 g1a = bias1f;
        g1a = MF(a1h_h, bh1_h, g1a);
        g1a = MF(a1h_h, bh1_l, g1a);
        g1a = MF(a1h_l, bh1_h, g1a);
        f32x4 g1b = zf;
        g1b = MF(a1x_h, bx_h, g1b);
        g1b = MF(a1x_h, bx_l, g1b);
        g1b = MF(a1x_l, bx_h, g1b);
        const f32x4 g1 = g1a + g1b;

        // lane-local activations (i,f,g,o of (kq, elem n))
        const float iv2 = sig2f(g2[0]);
        const float fv2 = sig2f(g2[1]);
        const float gg2 = fmaf(2.0f, sig2f(g2[2]), -1.0f);
        const float ov2 = sig2f(g2[3]);
        c2 = fmaf(fv2, c2, iv2 * gg2);
        const float h2n = ov2 * fmaf(2.0f, sig2f(M2 * c2), -1.0f);

        const float iv1 = sig2f(g1[0]);
        const float fv1 = sig2f(g1[1]);
        const float gg1 = fmaf(2.0f, sig2f(g1[2]), -1.0f);
        const float ov1 = sig2f(g1[3]);
        c1 = fmaf(fv1, c1, iv1 * gg1);
        const float h1n = ov1 * fmaf(2.0f, sig2f(M2 * c1), -1.0f);

        // frag-layout stores
        const int bw = (t + 1) & 1;
        HU h1hi, h1lo, h2hi, h2lo;
        h1hi.h = (_Float16)h1n;
        h1lo.h = (_Float16)(h1n - (float)h1hi.h);
        h2hi.h = (_Float16)h2n;
        h2lo.h = (_Float16)(h2n - (float)h2hi.h);
        lds[bw][0][n][pos] = okq ? h1hi.s : (u16)0;   // h1(t+1)
        lds[bw][1][n][pos] = okq ? h1lo.s : (u16)0;
        lds[bw][2][n][pos] = okq ? h2hi.s : (u16)0;   // h2(t)
        lds[bw][3][n][pos] = okq ? h2lo.s : (u16)0;

        lds_barrier();   // lgkm-only drain + s_barrier (no vmcnt)

        // next-step B frags (reads issued first; latency hides under convert)
        bh1_h = *reinterpret_cast<const half8*>(&lds[bw][0][n][8 * p]);
        bh1_l = *reinterpret_cast<const half8*>(&lds[bw][1][n][8 * p]);
        bh2_h = *reinterpret_cast<const half8*>(&lds[bw][2][n][8 * p]);
        bh2_l = *reinterpret_cast<const half8*>(&lds[bw][3][n][8 * p]);

        // convert xn = x(t+2) -> bx (issued a full step before its use);
        // then issue load of x(t+3) (a full step before ITS conversion).
        {
            F8 XH, XL;
#pragma unroll
            for (int e = 0; e < 8; ++e) { XH.e[e] = (_Float16)0.0f; XL.e[e] = (_Float16)0.0f; }
            if (p == 0) {
#pragma unroll
                for (int e = 0; e < 4; ++e) {
                    _Float16 t16 = (_Float16)xn[e];
                    XH.e[e] = t16; XL.e[e] = (_Float16)(xn[e] - (float)t16);
                }
            }
            bx_h = XH.h; bx_l = XL.h;
        }
        xn = xp[(t + 3 < T) ? (t + 3) : (T - 1)];

        // head: out(t) = Wlin @ h2(t) + blin (wave 7; rows 0-3 on p==0 lanes)
        if (w == 7) {
            f32x4 oh = blinf;
            oh = MF(alin_h, bh2_h, oh);
            oh = MF(alin_h, bh2_l, oh);
            oh = MF(alin_l, bh2_h, oh);
            if (p == 0) {
                v4f ov;
                ov.x = oh[0]; ov.y = oh[1]; ov.z = oh[2]; ov.w = oh[3];
                *reinterpret_cast<v4f*>(out + (((size_t)(b0 + n)) * T + t) * DOUT) = ov;
            }
        }
    }
}

extern "C" void kernel_launch(void* const* d_in, const int* in_sizes, int n_in,
                              void* d_out, int out_size, void* d_ws, size_t ws_size,
                              hipStream_t stream)
{
    const float* x    = (const float*)d_in[0];
    const float* Wih1 = (const float*)d_in[1];
    const float* bih1 = (const float*)d_in[2];
    const float* Whh1 = (const float*)d_in[3];
    const float* bhh1 = (const float*)d_in[4];
    const float* Wih2 = (const float*)d_in[5];
    const float* bih2 = (const float*)d_in[6];
    const float* Whh2 = (const float*)d_in[7];
    const float* bhh2 = (const float*)d_in[8];
    const float* Wlin = (const float*)d_in[9];
    const float* blin = (const float*)d_in[10];
    float* out = (float*)d_out;

    const int T = 1024;
    const int B = in_sizes[0] / (T * DIN);   // 2048

    hipLaunchKernelGGL(lstm2_kernel, dim3(B / NB), dim3(512), 0, stream,
                       x, Wih1, bih1, Whh1, bhh1, Wih2, bih2, Whh2, bhh2,
                       Wlin, blin, out, T);
}

// Round 11
// 743.359 us; speedup vs baseline: 1.5811x; 1.0251x over previous
//
#include <hip/hip_runtime.h>

typedef float f32x4 __attribute__((ext_vector_type(4)));
typedef float v4f  __attribute__((ext_vector_type(4)));
typedef _Float16 half8 __attribute__((ext_vector_type(8)));
typedef unsigned int u32;
typedef unsigned short u16;

#define HH 30
#define DIN 4
#define DOUT 4
#define NB 16      // batch elements per block
#define L2E 1.44269504088896340736f

#if __has_builtin(__builtin_amdgcn_exp2f)
#define EXP2F(v) __builtin_amdgcn_exp2f(v)
#else
#define EXP2F(v) exp2f(v)
#endif

// Pre-scaled sigmoid: -log2e (g rows: -2*log2e) folded into W and bias.
__device__ __forceinline__ float sig2f(float v) {
    return __builtin_amdgcn_rcpf(1.0f + EXP2F(v));
}

__device__ __forceinline__ f32x4 MF(half8 a, half8 b, f32x4 c) {
    return __builtin_amdgcn_mfma_f32_16x16x32_f16(a, b, c, 0, 0, 0);
}

union F8 { half8 h; _Float16 e[8]; u32 w[4]; };
union HU { _Float16 h; u16 s; };

// Workgroup barrier with LGKM-only drain (no vmcnt): cross-wave correctness
// only involves LDS; outstanding global x-prefetches stay in flight.
__device__ __forceinline__ void lds_barrier() {
    __builtin_amdgcn_sched_barrier(0);
    asm volatile("s_waitcnt lgkmcnt(0)" ::: "memory");
    __builtin_amdgcn_sched_barrier(0);
    __builtin_amdgcn_s_barrier();
    __builtin_amdgcn_sched_barrier(0);
}

// Layer-pipelined MFMA LSTM (R9 design; R10 was an infra failure — resubmit).
// One block = 16 waves = 16 batch elements.
// Waves 0-7 ("L1"): compute h1(s) at slot s      (needs h1(s-1), x(s)).
// Waves 8-15 ("L2"): compute h2(s-1) at slot s   (needs h1(s-1), h2(s-2));
//                    head out(s-2) at slot s (round-robin wave; reads the
//                    same bh2 regs = h2(s-2) every L2 wave already loaded).
// T+2 slots total. Per-wave critical chain is MINIMAL: 1 tile, parallel
// MFMA accumulators (depth = 1 MFMA + tree adds, not 3 chained), one
// activation set. L1's x-contribution is computed in exact f32 VALU one
// slot ahead (gx = Wih1@x + bias1, 16 FMAs) and used as MFMA C-init — no
// x MFMAs, no x f16 convert on the path.
// Gate rows interleaved (packed row = 4q + gate) -> lane-local c/h update.
// h transported via LDS in frag layout (u16 planes [n][40], <=2-way banks),
// double-buffered by slot parity; ONE lgkm-only barrier per slot.
__global__ __launch_bounds__(1024)
void lstm2_kernel(const float* __restrict__ x,
                  const float* __restrict__ Wih1, const float* __restrict__ bih1,
                  const float* __restrict__ Whh1, const float* __restrict__ bhh1,
                  const float* __restrict__ Wih2, const float* __restrict__ bih2,
                  const float* __restrict__ Whh2, const float* __restrict__ bhh2,
                  const float* __restrict__ Wlin, const float* __restrict__ blin,
                  float* __restrict__ out, int T)
{
    const int tid = threadIdx.x;
    const int w = tid >> 6;        // wave 0..15
    const int wt = w & 7;          // tile index within group
    const bool isL2 = (w >= 8);
    const int l = tid & 63;
    const int n = l & 15;          // elem col / A-row-in-tile
    const int p = l >> 4;          // quad index
    const int b0 = blockIdx.x * NB;
    const float M2 = -2.0f * L2E;  // tanh(c) = 2*sig2f(M2*c)-1

    // [buf][plane: 0=h1hi 1=h1lo 2=h2hi 3=h2lo][n][pos], stride 40 u16
    __shared__ __align__(16) u16 lds[2][4][16][40];
    {
        u32* z = reinterpret_cast<u32*>(&lds[0][0][0][0]);
        const int tot = 2 * 4 * 16 * 40 / 2;
        for (int i = tid; i < tot; i += 1024) z[i] = 0u;
    }

    // ---------- per-lane constants ----------
    const int gA = n & 3;                       // gate of this A row
    const float scA = (gA == 2) ? -2.0f * L2E : -L2E;
    const int qA = 4 * wt + (n >> 2);           // h-row of this A row
    const int kq = 4 * wt + p;                  // this lane's C-frag h-row
    const bool okq = (kq < HH);
    const int kqc = okq ? kq : 0;
    const int pos = ((kq & 15) >> 2) * 8 + (kq >> 4) * 4 + (kq & 3);

    // A-frags: L1 uses slot0 = Whh1; L2 uses slot0 = Wih2, slot1 = Whh2.
    half8 wA_h0, wA_l0, wA_h1, wA_l1;
    {
        F8 H0, L0, H1, L1v;
#pragma unroll
        for (int e = 0; e < 8; ++e) {
            const int k = 16 * (e >> 2) + 4 * p + (e & 3);
            const bool kok = (qA < HH && k < HH);
            float v0, v1;
            if (isL2) {
                v0 = kok ? Wih2[(gA * HH + qA) * HH + k] * scA : 0.0f;
                v1 = kok ? Whh2[(gA * HH + qA) * HH + k] * scA : 0.0f;
            } else {
                v0 = kok ? Whh1[(gA * HH + qA) * HH + k] * scA : 0.0f;
                v1 = 0.0f;
            }
            _Float16 t0 = (_Float16)v0, t1 = (_Float16)v1;
            H0.e[e] = t0; L0.e[e] = (_Float16)(v0 - (float)t0);
            H1.e[e] = t1; L1v.e[e] = (_Float16)(v1 - (float)t1);
        }
        wA_h0 = H0.h; wA_l0 = L0.h; wA_h1 = H1.h; wA_l1 = L1v.h;
    }

    // bias (pre-scaled) for this lane's 4 gate rows of kq
    f32x4 biasf;
#pragma unroll
    for (int r = 0; r < 4; ++r) {
        const float scr = (r == 2) ? -2.0f * L2E : -L2E;
        const float bv = isL2 ? (bih2[r * HH + kqc] + bhh2[r * HH + kqc])
                              : (bih1[r * HH + kqc] + bhh1[r * HH + kqc]);
        biasf[r] = okq ? bv * scr : 0.0f;
    }

    // L1: per-lane x weights (exact f32), 4 gates x DIN
    float wxs[4][DIN];
#pragma unroll
    for (int r = 0; r < 4; ++r) {
        const float scr = (r == 2) ? -2.0f * L2E : -L2E;
#pragma unroll
        for (int c = 0; c < DIN; ++c)
            wxs[r][c] = (!isL2 && okq) ? Wih1[(r * HH + kqc) * DIN + c] * scr : 0.0f;
    }

    // head frags (L2 only uses)
    half8 alin_h, alin_l;
    f32x4 blinf;
    {
        F8 Lh, Ll;
#pragma unroll
        for (int e = 0; e < 8; ++e) {
            const int k = 16 * (e >> 2) + 4 * p + (e & 3);
            float v = (isL2 && n < DOUT && k < HH) ? Wlin[n * HH + k] : 0.0f;
            _Float16 t16 = (_Float16)v;
            Lh.e[e] = t16; Ll.e[e] = (_Float16)(v - (float)t16);
        }
        alin_h = Lh.h; alin_l = Ll.h;
#pragma unroll
        for (int r = 0; r < 4; ++r)
            blinf[r] = (p == 0) ? blin[r] : 0.0f;
    }

    float cst = 0.0f;              // c1 (L1 waves) or c2 (L2 waves)
    half8 bh1_h = {}, bh1_l = {}, bh2_h = {}, bh2_l = {};   // zero: h(-1)=0

    const v4f* xp = reinterpret_cast<const v4f*>(x) + (size_t)(b0 + n) * T;

    // gx pipeline (L1 only): gx_cur = Wih1@x(s) + bias1 (exact f32)
    f32x4 gx_cur = biasf;
    v4f xn = {};
    if (!isL2) {
        const v4f x0 = xp[0];
#pragma unroll
        for (int r = 0; r < 4; ++r)
#pragma unroll
            for (int c = 0; c < DIN; ++c)
                gx_cur[r] = fmaf(wxs[r][c], x0[c], gx_cur[r]);
        xn = xp[(T > 1) ? 1 : 0];
    }

    __syncthreads();   // zero-init visible

    const f32x4 zf = {0.0f, 0.0f, 0.0f, 0.0f};
    const int TS = T + 2;

    for (int s = 0; s < TS; ++s) {
        if (!isL2) {
            // ---- L1: h1(s) = act(Whh1 @ h1(s-1) + gx(s)) ----
            f32x4 a = MF(wA_h0, bh1_h, gx_cur);   // parallel accumulators
            f32x4 b = MF(wA_h0, bh1_l, zf);
            f32x4 c = MF(wA_l0, bh1_h, zf);
            const f32x4 g = (a + b) + c;

            const float iv = sig2f(g[0]);
            const float fv = sig2f(g[1]);
            const float gg = fmaf(2.0f, sig2f(g[2]), -1.0f);
            const float ov = sig2f(g[3]);
            cst = fmaf(fv, cst, iv * gg);
            const float r = sig2f(M2 * cst);
            const float hn = fmaf(2.0f * ov, r, -ov);   // o*tanh(c)

            HU hi, lo;
            hi.h = (_Float16)hn;
            lo.h = (_Float16)(hn - (float)hi.h);
            lds[s & 1][0][n][pos] = okq ? hi.s : (u16)0;
            lds[s & 1][1][n][pos] = okq ? lo.s : (u16)0;
        } else {
            if (s >= 1) {
                // ---- L2: h2(s-1) = act(Wih2@h1(s-1) + Whh2@h2(s-2) + b2) ----
                f32x4 a = MF(wA_h0, bh1_h, biasf);
                f32x4 b = MF(wA_h0, bh1_l, zf);
                f32x4 c = MF(wA_l0, bh1_h, zf);
                f32x4 d = MF(wA_h1, bh2_h, zf);
                f32x4 e = MF(wA_h1, bh2_l, zf);
                f32x4 f = MF(wA_l1, bh2_h, zf);
                const f32x4 g = ((a + b) + (c + d)) + (e + f);

                const float iv = sig2f(g[0]);
                const float fv = sig2f(g[1]);
                const float gg = fmaf(2.0f, sig2f(g[2]), -1.0f);
                const float ov = sig2f(g[3]);
                cst = fmaf(fv, cst, iv * gg);
                const float r = sig2f(M2 * cst);
                const float hn = fmaf(2.0f * ov, r, -ov);

                HU hi, lo;
                hi.h = (_Float16)hn;
                lo.h = (_Float16)(hn - (float)hi.h);
                lds[(s + 1) & 1][2][n][pos] = okq ? hi.s : (u16)0;
                lds[(s + 1) & 1][3][n][pos] = okq ? lo.s : (u16)0;
            }
            // ---- head: out(s-2) = Wlin @ h2(s-2) + blin (round-robin) ----
            if (s >= 2 && w == 8 + (s & 7)) {
                f32x4 oh = blinf;                 // bh2 regs = h2(s-2)
                oh = MF(alin_h, bh2_h, oh);
                oh = MF(alin_h, bh2_l, oh);
                oh = MF(alin_l, bh2_h, oh);
                if (p == 0) {
                    v4f ov4;
                    ov4.x = oh[0]; ov4.y = oh[1]; ov4.z = oh[2]; ov4.w = oh[3];
                    *reinterpret_cast<v4f*>(
                        out + (((size_t)(b0 + n)) * T + (s - 2)) * DOUT) = ov4;
                }
            }
        }

        lds_barrier();   // lgkm-only drain + s_barrier

        // reads for slot s+1: h1(s) @ buf[s&1]; h2(s-1) @ buf[(s+1)&1]
        bh1_h = *reinterpret_cast<const half8*>(&lds[s & 1][0][n][8 * p]);
        bh1_l = *reinterpret_cast<const half8*>(&lds[s & 1][1][n][8 * p]);
        if (isL2) {
            bh2_h = *reinterpret_cast<const half8*>(&lds[(s + 1) & 1][2][n][8 * p]);
            bh2_l = *reinterpret_cast<const half8*>(&lds[(s + 1) & 1][3][n][8 * p]);
        } else {
            // off-path: gx(s+1) from xn, then prefetch x(s+2)
            f32x4 gxn = biasf;
#pragma unroll
            for (int r = 0; r < 4; ++r)
#pragma unroll
                for (int c = 0; c < DIN; ++c)
                    gxn[r] = fmaf(wxs[r][c], xn[c], gxn[r]);
            gx_cur = gxn;
            xn = xp[(s + 2 < T) ? (s + 2) : (T - 1)];
        }
    }
}

extern "C" void kernel_launch(void* const* d_in, const int* in_sizes, int n_in,
                              void* d_out, int out_size, void* d_ws, size_t ws_size,
                              hipStream_t stream)
{
    const float* x    = (const float*)d_in[0];
    const float* Wih1 = (const float*)d_in[1];
    const float* bih1 = (const float*)d_in[2];
    const float* Whh1 = (const float*)d_in[3];
    const float* bhh1 = (const float*)d_in[4];
    const float* Wih2 = (const float*)d_in[5];
    const float* bih2 = (const float*)d_in[6];
    const float* Whh2 = (const float*)d_in[7];
    const float* bhh2 = (const float*)d_in[8];
    const float* Wlin = (const float*)d_in[9];
    const float* blin = (const float*)d_in[10];
    float* out = (float*)d_out;

    const int T = 1024;
    const int B = in_sizes[0] / (T * DIN);   // 2048

    hipLaunchKernelGGL(lstm2_kernel, dim3(B / NB), dim3(1024), 0, stream,
                       x, Wih1, bih1, Whh1, bhh1, Wih2, bih2, Whh2, bhh2,
                       Wlin, blin, out, T);
}